// Round 11
// baseline (514.276 us; speedup 1.0000x reference)
//
#include <hip/hip_runtime.h>

#define CH 64
#define CHUNK 4096
#define BSHIFT 8          // 256 nodes per bucket
#define NBUCK 196         // ceil(50000 / 256); requires N < 65536 (16-bit packing)

__device__ __forceinline__ unsigned short f2bf_rne(float f) {
    unsigned int u = __float_as_uint(f);
    u += 0x7fffu + ((u >> 16) & 1u);   // round to nearest even
    return (unsigned short)(u >> 16);
}
__device__ __forceinline__ float bf_lo(unsigned int q) {
    return __uint_as_float(q << 16);
}
__device__ __forceinline__ float bf_hi(unsigned int q) {
    return __uint_as_float(q & 0xffff0000u);
}
__device__ __forceinline__ unsigned int pack2bf(float lo, float hi) {
    return (unsigned int)f2bf_rne(lo) | ((unsigned int)f2bf_rne(hi) << 16);
}

// ---------- K0: layer-1 GEMM (raw messages, no dinv) + global bucket histogram ----------
template <int K>
__global__ __launch_bounds__(256) void gemm1_hist_kernel(
        const float* __restrict__ X, const float* __restrict__ W,
        unsigned short* __restrict__ G, int N,
        const int* __restrict__ dst, int* __restrict__ bucket_cnt, int E,
        int gemm_blocks) {
    constexpr int KC  = 64;
    constexpr int XLD = KC + 4;
    __shared__ float Xs[64 * XLD];        // 17408 B
    __shared__ float Wls[KC * CH];        // 16384 B
    __shared__ int hist[256];             // 1024 B
    int tid = threadIdx.x;

    if (blockIdx.x >= gemm_blocks) {
        int cid = blockIdx.x - gemm_blocks;
        int e0 = cid * CHUNK;
        int total = min(CHUNK, E - e0);
        hist[tid] = 0;
        __syncthreads();
        for (int i = tid; i < total; i += 256)
            atomicAdd(&hist[dst[e0 + i] >> BSHIFT], 1);
        __syncthreads();
        if (tid < NBUCK && hist[tid]) atomicAdd(&bucket_cnt[tid], hist[tid]);
        return;
    }

    // ---- gemm part: G = bf16(X @ W) ----
    int tx  = tid & 15;
    int ty  = tid >> 4;
    int row_tile = blockIdx.x * 64;
    int r0 = ty * 4;
    float acc[4][4] = {{0.f}};

    for (int kc = 0; kc < K; kc += KC) {
        __syncthreads();
#pragma unroll
        for (int t = 0; t < 4; ++t) {
            int idx = tid + t * 256;
            int row = idx >> 4;
            int k4  = idx & 15;
            int grow = row_tile + row;
            const float4* xs = (const float4*)(X + (size_t)min(grow, N - 1) * K + kc);
            *(float4*)&Xs[row * XLD + 4 * k4] = xs[k4];
        }
#pragma unroll
        for (int t = 0; t < 4; ++t) {
            int idx = tid + t * 256;
            *(float4*)&Wls[idx * 4] = ((const float4*)(W + (size_t)kc * CH))[idx];
        }
        __syncthreads();
#pragma unroll
        for (int kk = 0; kk < KC; kk += 4) {
            float xr[4][4], wr[4][4];
#pragma unroll
            for (int i = 0; i < 4; ++i) {
                float4 v = *(const float4*)&Xs[(r0 + i) * XLD + kk];
                xr[i][0] = v.x; xr[i][1] = v.y; xr[i][2] = v.z; xr[i][3] = v.w;
            }
#pragma unroll
            for (int j = 0; j < 4; ++j) {
                float4 v = *(const float4*)&Wls[(kk + j) * CH + 4 * tx];
                wr[j][0] = v.x; wr[j][1] = v.y; wr[j][2] = v.z; wr[j][3] = v.w;
            }
#pragma unroll
            for (int i = 0; i < 4; ++i)
#pragma unroll
                for (int j = 0; j < 4; ++j)
#pragma unroll
                    for (int c = 0; c < 4; ++c)
                        acc[i][c] = fmaf(xr[i][j], wr[j][c], acc[i][c]);
        }
    }
#pragma unroll
    for (int i = 0; i < 4; ++i) {
        int r = row_tile + r0 + i;
        if (r < N) {
            ushort4 o;
            o.x = f2bf_rne(acc[i][0]);
            o.y = f2bf_rne(acc[i][1]);
            o.z = f2bf_rne(acc[i][2]);
            o.w = f2bf_rne(acc[i][3]);
            ((ushort4*)G)[(size_t)r * 16 + tx] = o;
        }
    }
}

// ---------- pass 2: block 0: 196-entry scan -> base+cursor; block 1: gptr ----------
__global__ __launch_bounds__(256) void scan_gptr_kernel(
        const int* __restrict__ cnt,
        int* __restrict__ bucket_base, int* __restrict__ cursor,
        int* __restrict__ rowptr,
        const int* __restrict__ batch, int* __restrict__ gptr,
        int N, int E, int NG) {
    if (blockIdx.x == 0) {
        __shared__ int sc[256];
        int t = threadIdx.x;
        int c = (t < NBUCK) ? cnt[t] : 0;
        sc[t] = c;
        __syncthreads();
        for (int off = 1; off < 256; off <<= 1) {
            int v = (t >= off) ? sc[t - off] : 0;
            __syncthreads();
            sc[t] += v;
            __syncthreads();
        }
        if (t < NBUCK) { bucket_base[t] = sc[t] - c; cursor[t] = sc[t] - c; }
        if (t == NBUCK - 1) bucket_base[NBUCK] = sc[t];
        if (t == 0) rowptr[N] = E;
    } else {
        for (int g = threadIdx.x; g <= NG; g += 256) {
            if (g == NG) { gptr[NG] = N; continue; }
            int lo = 0, hi = N;
            while (lo < hi) {
                int mid = (lo + hi) >> 1;
                if (batch[mid] < g) lo = mid + 1; else hi = mid;
            }
            gptr[g] = lo;
        }
    }
}

// ---------- pass 3: bin edges into bucket regions ----------
__global__ __launch_bounds__(256) void bin_kernel(
        const int* __restrict__ src, const int* __restrict__ dst,
        int* __restrict__ cursor, unsigned int* __restrict__ pairs, int E) {
    __shared__ unsigned int stage[CHUNK];                 // 16 KB
    __shared__ int hist[256], sc[256], lbase[256], lcur[256], gbase[256];
    int tid = threadIdx.x;
    int e0 = blockIdx.x * CHUNK;
    int total = min(CHUNK, E - e0);
    hist[tid] = 0;
    __syncthreads();
    for (int i = tid; i < total; i += 256)
        atomicAdd(&hist[dst[e0 + i] >> BSHIFT], 1);
    __syncthreads();
    sc[tid] = hist[tid];
    __syncthreads();
    for (int off = 1; off < 256; off <<= 1) {
        int v = (tid >= off) ? sc[tid - off] : 0;
        __syncthreads();
        sc[tid] += v;
        __syncthreads();
    }
    lbase[tid] = sc[tid] - hist[tid];
    lcur[tid]  = sc[tid] - hist[tid];
    if (tid < NBUCK && hist[tid] > 0) gbase[tid] = atomicAdd(&cursor[tid], hist[tid]);
    __syncthreads();
    for (int i = tid; i < total; i += 256) {
        unsigned int s = (unsigned int)src[e0 + i];
        unsigned int d = (unsigned int)dst[e0 + i];
        int pos = atomicAdd(&lcur[d >> BSHIFT], 1);
        stage[pos] = (d << 16) | s;
    }
    __syncthreads();
    for (int i = tid; i < total; i += 256) {
        unsigned int p = stage[i];
        int b = (int)(p >> 24);
        pairs[gbase[b] + (i - lbase[b])] = p;
    }
}

// ---------- pass 4: counting sort -> csr(ushort), rowptr, dinv, deg(+hist) ----------
__global__ __launch_bounds__(256) void bucket_sort_kernel(
        const unsigned int* __restrict__ pairs, const int* __restrict__ base,
        unsigned short* __restrict__ csr, int* __restrict__ rowptr,
        float* __restrict__ dinv, unsigned char* __restrict__ deg,
        int* __restrict__ deghist, int N) {
    __shared__ int cntl[256], sc[256], cur[256];
    int tid = threadIdx.x;
    int b = blockIdx.x;
    int pbase = base[b], pend = base[b + 1];
    int cnt = pend - pbase;
    cntl[tid] = 0;
    __syncthreads();
    for (int i = tid; i < cnt; i += 256)
        atomicAdd(&cntl[(pairs[pbase + i] >> 16) & 255u], 1);
    __syncthreads();
    sc[tid] = cntl[tid];
    __syncthreads();
    for (int off = 1; off < 256; off <<= 1) {
        int v = (tid >= off) ? sc[tid - off] : 0;
        __syncthreads();
        sc[tid] += v;
        __syncthreads();
    }
    int excl = sc[tid] - cntl[tid];
    cur[tid] = excl;
    int v = (b << BSHIFT) + tid;
    if (v < N) {
        rowptr[v] = pbase + excl;
        dinv[v] = rsqrtf((float)(cntl[tid] + 1));  // deg = indeg + 1 (self loop)
        int d = min(cntl[tid], 255);
        deg[v] = (unsigned char)d;
        atomicAdd(&deghist[d], 1);
    }
    __syncthreads();
    for (int i = tid; i < cnt; i += 256) {
        unsigned int p = pairs[pbase + i];
        int pos = atomicAdd(&cur[(p >> 16) & 255u], 1);
        csr[pbase + pos] = (unsigned short)(p & 0xffffu);
    }
}

// ---------- degree-bin exclusive scan (1 block) ----------
__global__ __launch_bounds__(256) void deg_scan_kernel(
        const int* __restrict__ deghist, int* __restrict__ degcur) {
    __shared__ int sc[256];
    int t = threadIdx.x;
    int c = deghist[t];
    sc[t] = c;
    __syncthreads();
    for (int off = 1; off < 256; off <<= 1) {
        int v = (t >= off) ? sc[t - off] : 0;
        __syncthreads();
        sc[t] += v;
        __syncthreads();
    }
    degcur[t] = sc[t] - c;  // exclusive
}

// ---------- build degree-sorted node permutation ----------
__global__ __launch_bounds__(256) void perm_kernel(
        const unsigned char* __restrict__ deg, int* __restrict__ degcur,
        int* __restrict__ perm, int N) {
    int v = blockIdx.x * 256 + threadIdx.x;
    if (v < N) {
        int p = atomicAdd(&degcur[deg[v]], 1);
        perm[p] = v;
    }
}

// ---------- gather aggregation (degree-sorted order, 2-edge pipeline) ----------
// 8 nodes/wave, 8 lanes/node (uint4 = 8 bf16 channels). perm groups nodes of
// near-equal degree into each wave -> wave-max loop bound ~= mean degree.
template <bool PRESCALED, bool F32OUT>
__global__ __launch_bounds__(256) void aggregate_kernel(
        const unsigned short* __restrict__ G, const int* __restrict__ rowptr,
        const unsigned short* __restrict__ csr, const float* __restrict__ dinv,
        const int* __restrict__ perm,
        void* __restrict__ Out, int N, int E, int relu) {
    int lane = threadIdx.x & 63;
    int w = (blockIdx.x * 256 + threadIdx.x) >> 6;
    int grp = lane >> 3, cl = lane & 7;
    int idx = w * 8 + grp;
    bool valid = idx < N;
    int v = perm[valid ? idx : N - 1];
    int beg = rowptr[v];
    int cnt = valid ? rowptr[v + 1] - beg : 0;
    int mx = cnt;
    mx = max(mx, __shfl_xor(mx, 8));
    mx = max(mx, __shfl_xor(mx, 16));
    mx = max(mx, __shfl_xor(mx, 32));

    const uint4* __restrict__ G4 = (const uint4*)G;
    float a0 = 0.f, a1 = 0.f, a2 = 0.f, a3 = 0.f;
    float a4 = 0.f, a5 = 0.f, a6 = 0.f, a7 = 0.f;
    float b0 = 0.f, b1 = 0.f, b2 = 0.f, b3 = 0.f;
    float b4 = 0.f, b5 = 0.f, b6 = 0.f, b7 = 0.f;
    int nit = (mx + 1) >> 1;
    for (int it = 0; it < nit; ++it) {
        int i0 = 2 * it, i1 = i0 + 1;
        int e0 = min(beg + i0, E - 1);
        int e1 = min(beg + i1, E - 1);
        bool ok0 = i0 < cnt, ok1 = i1 < cnt;
        int u0 = ok0 ? (int)csr[e0] : 0;
        int u1 = ok1 ? (int)csr[e1] : 0;
        float s0, s1;
        if (PRESCALED) { s0 = ok0 ? 1.f : 0.f;        s1 = ok1 ? 1.f : 0.f; }
        else           { s0 = ok0 ? dinv[u0] : 0.f;   s1 = ok1 ? dinv[u1] : 0.f; }
        uint4 q0 = G4[(size_t)u0 * 8 + cl];
        uint4 q1 = G4[(size_t)u1 * 8 + cl];
        a0 = fmaf(bf_lo(q0.x), s0, a0); a1 = fmaf(bf_hi(q0.x), s0, a1);
        a2 = fmaf(bf_lo(q0.y), s0, a2); a3 = fmaf(bf_hi(q0.y), s0, a3);
        a4 = fmaf(bf_lo(q0.z), s0, a4); a5 = fmaf(bf_hi(q0.z), s0, a5);
        a6 = fmaf(bf_lo(q0.w), s0, a6); a7 = fmaf(bf_hi(q0.w), s0, a7);
        b0 = fmaf(bf_lo(q1.x), s1, b0); b1 = fmaf(bf_hi(q1.x), s1, b1);
        b2 = fmaf(bf_lo(q1.y), s1, b2); b3 = fmaf(bf_hi(q1.y), s1, b3);
        b4 = fmaf(bf_lo(q1.z), s1, b4); b5 = fmaf(bf_hi(q1.z), s1, b5);
        b6 = fmaf(bf_lo(q1.w), s1, b6); b7 = fmaf(bf_hi(q1.w), s1, b7);
    }
    a0 += b0; a1 += b1; a2 += b2; a3 += b3;
    a4 += b4; a5 += b5; a6 += b6; a7 += b7;
    if (valid) {
        uint4 q = G4[(size_t)v * 8 + cl];   // self-loop term
        float d = dinv[v];
        float sv = PRESCALED ? 1.f : d;
        float o0 = (a0 + bf_lo(q.x) * sv) * d, o1 = (a1 + bf_hi(q.x) * sv) * d;
        float o2 = (a2 + bf_lo(q.y) * sv) * d, o3 = (a3 + bf_hi(q.y) * sv) * d;
        float o4 = (a4 + bf_lo(q.z) * sv) * d, o5 = (a5 + bf_hi(q.z) * sv) * d;
        float o6 = (a6 + bf_lo(q.w) * sv) * d, o7 = (a7 + bf_hi(q.w) * sv) * d;
        if (relu) {
            o0 = fmaxf(o0, 0.f); o1 = fmaxf(o1, 0.f); o2 = fmaxf(o2, 0.f);
            o3 = fmaxf(o3, 0.f); o4 = fmaxf(o4, 0.f); o5 = fmaxf(o5, 0.f);
            o6 = fmaxf(o6, 0.f); o7 = fmaxf(o7, 0.f);
        }
        if (F32OUT) {
            float4 w0 = {o0, o1, o2, o3}, w1 = {o4, o5, o6, o7};
            ((float4*)Out)[(size_t)v * 16 + cl * 2]     = w0;
            ((float4*)Out)[(size_t)v * 16 + cl * 2 + 1] = w1;
        } else {
            uint4 p;
            p.x = pack2bf(o0, o1); p.y = pack2bf(o2, o3);
            p.z = pack2bf(o4, o5); p.w = pack2bf(o6, o7);
            ((uint4*)Out)[(size_t)v * 8 + cl] = p;
        }
    }
}

// ---------- GEMM (bf16 input, K=64) + dinv prescale -> bf16 ----------
__global__ __launch_bounds__(256) void gemm_bf16_kernel(
        const unsigned short* __restrict__ Xbf, const float* __restrict__ W,
        const float* __restrict__ dinv, unsigned short* __restrict__ G, int N) {
    constexpr int XLDU = 36;
    __shared__ unsigned int Xs[64 * XLDU];  // 9216 B
    __shared__ float Wls[64 * CH];          // 16384 B
    int tid = threadIdx.x;
    int tx  = tid & 15;
    int ty  = tid >> 4;
    int row_tile = blockIdx.x * 64;
    int r0 = ty * 4;
    float acc[4][4] = {{0.f}};

#pragma unroll
    for (int t = 0; t < 2; ++t) {
        int idx = tid + t * 256;
        int row = idx >> 3;
        int k4  = idx & 7;
        int grow = row_tile + row;
        uint4 v = ((const uint4*)Xbf)[(size_t)min(grow, N - 1) * 8 + k4];
        *(uint4*)&Xs[row * XLDU + 4 * k4] = v;
    }
#pragma unroll
    for (int t = 0; t < 4; ++t) {
        int idx = tid + t * 256;
        *(float4*)&Wls[idx * 4] = ((const float4*)W)[idx];
    }
    __syncthreads();
#pragma unroll
    for (int kk = 0; kk < 64; kk += 4) {
        float xr[4][4], wr[4][4];
#pragma unroll
        for (int i = 0; i < 4; ++i) {
            uint2 q = *(const uint2*)&Xs[(r0 + i) * XLDU + (kk >> 1)];
            xr[i][0] = bf_lo(q.x); xr[i][1] = bf_hi(q.x);
            xr[i][2] = bf_lo(q.y); xr[i][3] = bf_hi(q.y);
        }
#pragma unroll
        for (int j = 0; j < 4; ++j) {
            float4 v = *(const float4*)&Wls[(kk + j) * CH + 4 * tx];
            wr[j][0] = v.x; wr[j][1] = v.y; wr[j][2] = v.z; wr[j][3] = v.w;
        }
#pragma unroll
        for (int i = 0; i < 4; ++i)
#pragma unroll
            for (int j = 0; j < 4; ++j)
#pragma unroll
                for (int c = 0; c < 4; ++c)
                    acc[i][c] = fmaf(xr[i][j], wr[j][c], acc[i][c]);
    }
#pragma unroll
    for (int i = 0; i < 4; ++i) {
        int r = row_tile + r0 + i;
        if (r < N) {
            float d = dinv[r];
            ushort4 o;
            o.x = f2bf_rne(acc[i][0] * d);
            o.y = f2bf_rne(acc[i][1] * d);
            o.z = f2bf_rne(acc[i][2] * d);
            o.w = f2bf_rne(acc[i][3] * d);
            ((ushort4*)G)[(size_t)r * 16 + tx] = o;
        }
    }
}

// ---------- fused mean-pool + linear head ----------
__global__ __launch_bounds__(64) void pool_head_kernel(
        const float* __restrict__ H, const int* __restrict__ gptr,
        const float* __restrict__ Wl, const float* __restrict__ bl,
        float* __restrict__ out, int NG) {
    int g = blockIdx.x;
    int lane = threadIdx.x;  // 64 = CH
    int s = gptr[g], e = gptr[g + 1];
    float acc = 0.f;
    for (int v = s; v < e; ++v) acc += H[(size_t)v * CH + lane];
    float c = (float)(e - s);
    float mean = (c > 0.f) ? acc / c : 0.f;
    for (int o = 0; o < 10; ++o) {
        float t = mean * Wl[lane * 10 + o];
        for (int off = 32; off > 0; off >>= 1) t += __shfl_down(t, off);
        if (lane == 0) out[g * 10 + o] = t + bl[o];
    }
}

extern "C" void kernel_launch(void* const* d_in, const int* in_sizes, int n_in,
                              void* d_out, int out_size, void* d_ws, size_t ws_size,
                              hipStream_t stream) {
    const float* x     = (const float*)d_in[0];
    const int*   ei    = (const int*)d_in[1];
    const int*   batch = (const int*)d_in[2];
    const float* W1    = (const float*)d_in[3];
    const float* W2    = (const float*)d_in[4];
    const float* W3    = (const float*)d_in[5];
    const float* Wl    = (const float*)d_in[6];
    const float* bl    = (const float*)d_in[7];
    float* out = (float*)d_out;

    const int N  = in_sizes[0] / 128;  // 50000 (< 65536)
    const int E  = in_sizes[1] / 2;    // 1250000
    const int NG = out_size / 10;      // 500

    const int* src = ei;
    const int* dst = ei + E;

    const int cb = (E + CHUNK - 1) / CHUNK;  // 306

    // workspace carve-out (256B aligned)
    char* ws = (char*)d_ws;
    size_t off = 0;
    auto alloc = [&](size_t bytes) -> void* {
        void* p = ws + off;
        off += bytes;
        off = (off + 255) & ~(size_t)255;
        return p;
    };
    int*   bucket_cnt  = (int*)alloc((size_t)NBUCK * 4);     // padded to 1024B
    int*   deghist     = (int*)alloc(256 * 4);               // adjacent: one memset
    int*   bucket_base = (int*)alloc((size_t)(NBUCK + 1) * 4);
    int*   cursor      = (int*)alloc((size_t)NBUCK * 4);
    int*   degcur      = (int*)alloc(256 * 4);
    unsigned short* csr = (unsigned short*)alloc((size_t)(E + 64) * 2);
    int*   rowptr = (int*)alloc((size_t)(N + 1) * 4);
    float* dinv   = (float*)alloc((size_t)N * 4);
    unsigned char* deg = (unsigned char*)alloc((size_t)N);
    int*   perm   = (int*)alloc((size_t)N * 4);
    int*   gptrb  = (int*)alloc((size_t)(NG + 1) * 4);
    unsigned short* GA = (unsigned short*)alloc((size_t)N * CH * 2);  // 6.4MB
    unsigned short* GB = (unsigned short*)alloc((size_t)N * CH * 2);  // 6.4MB
    float* hbuf   = (float*)alloc((size_t)N * CH * 4);   // 12.8MB; aliases pairs (5MB)
    unsigned int* pairs = (unsigned int*)hbuf;  // sort consumes before agg3 writes hbuf

    // zero bucket_cnt (1024B incl. pad) + deghist (1024B) in one memset
    hipMemsetAsync(bucket_cnt, 0, 2048, stream);

    int gb = (N + 63) / 64;            // 782 gemm tiles
    int ab = ((N + 7) / 8 + 3) / 4;    // agg: 8 nodes/wave, 4 waves/block
    int nb = (N + 255) / 256;          // 196

    // K0: gemm1 (raw messages) + histogram chunks in one launch
    gemm1_hist_kernel<128><<<gb + cb, 256, 0, stream>>>(x, W1, GA, N,
                                                        dst, bucket_cnt, E, gb);
    scan_gptr_kernel<<<2, 256, 0, stream>>>(bucket_cnt, bucket_base, cursor,
                                            rowptr, batch, gptrb, N, E, NG);
    bin_kernel<<<cb, 256, 0, stream>>>(src, dst, cursor, pairs, E);
    bucket_sort_kernel<<<NBUCK, 256, 0, stream>>>(pairs, bucket_base, csr, rowptr,
                                                  dinv, deg, deghist, N);
    deg_scan_kernel<<<1, 256, 0, stream>>>(deghist, degcur);
    perm_kernel<<<nb, 256, 0, stream>>>(deg, degcur, perm, N);

    // layer 1 aggregate (messages NOT prescaled -> multiply dinv[u] per edge)
    aggregate_kernel<false, false><<<ab, 256, 0, stream>>>(GA, rowptr, csr, dinv,
                                                           perm, GB, N, E, 1);
    // layer 2
    gemm_bf16_kernel<<<gb, 256, 0, stream>>>(GB, W2, dinv, GA, N);
    aggregate_kernel<true, false><<<ab, 256, 0, stream>>>(GA, rowptr, csr, dinv,
                                                          perm, GB, N, E, 1);
    // layer 3
    gemm_bf16_kernel<<<gb, 256, 0, stream>>>(GB, W3, dinv, GA, N);
    aggregate_kernel<true, true><<<ab, 256, 0, stream>>>(GA, rowptr, csr, dinv,
                                                         perm, hbuf, N, E, 0);

    // mean pool + linear head
    pool_head_kernel<<<NG, 64, 0, stream>>>(hbuf, gptrb, Wl, bl, out, NG);
}

// Round 12
// 263.870 us; speedup vs baseline: 1.9490x; 1.9490x over previous
//
#include <hip/hip_runtime.h>

#define CH 64
#define CHUNK 4096
#define BSHIFT 8          // 256 nodes per bucket
#define NBUCK 196         // ceil(50000 / 256); requires N < 65536 (16-bit packing)

__device__ __forceinline__ unsigned short f2bf_rne(float f) {
    unsigned int u = __float_as_uint(f);
    u += 0x7fffu + ((u >> 16) & 1u);   // round to nearest even
    return (unsigned short)(u >> 16);
}
__device__ __forceinline__ float bf_lo(unsigned int q) {
    return __uint_as_float(q << 16);
}
__device__ __forceinline__ float bf_hi(unsigned int q) {
    return __uint_as_float(q & 0xffff0000u);
}
__device__ __forceinline__ unsigned int pack2bf(float lo, float hi) {
    return (unsigned int)f2bf_rne(lo) | ((unsigned int)f2bf_rne(hi) << 16);
}

// ---------- K0: layer-1 GEMM (raw messages, no dinv) + global bucket histogram ----------
template <int K>
__global__ __launch_bounds__(256) void gemm1_hist_kernel(
        const float* __restrict__ X, const float* __restrict__ W,
        unsigned short* __restrict__ G, int N,
        const int* __restrict__ dst, int* __restrict__ bucket_cnt, int E,
        int gemm_blocks) {
    constexpr int KC  = 64;
    constexpr int XLD = KC + 4;
    __shared__ float Xs[64 * XLD];        // 17408 B
    __shared__ float Wls[KC * CH];        // 16384 B
    __shared__ int hist[256];             // 1024 B
    int tid = threadIdx.x;

    if (blockIdx.x >= gemm_blocks) {
        int cid = blockIdx.x - gemm_blocks;
        int e0 = cid * CHUNK;
        int total = min(CHUNK, E - e0);
        hist[tid] = 0;
        __syncthreads();
        for (int i = tid; i < total; i += 256)
            atomicAdd(&hist[dst[e0 + i] >> BSHIFT], 1);
        __syncthreads();
        if (tid < NBUCK && hist[tid]) atomicAdd(&bucket_cnt[tid], hist[tid]);
        return;
    }

    // ---- gemm part: G = bf16(X @ W) ----
    int tx  = tid & 15;
    int ty  = tid >> 4;
    int row_tile = blockIdx.x * 64;
    int r0 = ty * 4;
    float acc[4][4] = {{0.f}};

    for (int kc = 0; kc < K; kc += KC) {
        __syncthreads();
#pragma unroll
        for (int t = 0; t < 4; ++t) {
            int idx = tid + t * 256;
            int row = idx >> 4;
            int k4  = idx & 15;
            int grow = row_tile + row;
            const float4* xs = (const float4*)(X + (size_t)min(grow, N - 1) * K + kc);
            *(float4*)&Xs[row * XLD + 4 * k4] = xs[k4];
        }
#pragma unroll
        for (int t = 0; t < 4; ++t) {
            int idx = tid + t * 256;
            *(float4*)&Wls[idx * 4] = ((const float4*)(W + (size_t)kc * CH))[idx];
        }
        __syncthreads();
#pragma unroll
        for (int kk = 0; kk < KC; kk += 4) {
            float xr[4][4], wr[4][4];
#pragma unroll
            for (int i = 0; i < 4; ++i) {
                float4 v = *(const float4*)&Xs[(r0 + i) * XLD + kk];
                xr[i][0] = v.x; xr[i][1] = v.y; xr[i][2] = v.z; xr[i][3] = v.w;
            }
#pragma unroll
            for (int j = 0; j < 4; ++j) {
                float4 v = *(const float4*)&Wls[(kk + j) * CH + 4 * tx];
                wr[j][0] = v.x; wr[j][1] = v.y; wr[j][2] = v.z; wr[j][3] = v.w;
            }
#pragma unroll
            for (int i = 0; i < 4; ++i)
#pragma unroll
                for (int j = 0; j < 4; ++j)
#pragma unroll
                    for (int c = 0; c < 4; ++c)
                        acc[i][c] = fmaf(xr[i][j], wr[j][c], acc[i][c]);
        }
    }
#pragma unroll
    for (int i = 0; i < 4; ++i) {
        int r = row_tile + r0 + i;
        if (r < N) {
            ushort4 o;
            o.x = f2bf_rne(acc[i][0]);
            o.y = f2bf_rne(acc[i][1]);
            o.z = f2bf_rne(acc[i][2]);
            o.w = f2bf_rne(acc[i][3]);
            ((ushort4*)G)[(size_t)r * 16 + tx] = o;
        }
    }
}

// ---------- pass 2: block 0: 196-entry scan -> base+cursor; block 1: gptr ----------
__global__ __launch_bounds__(256) void scan_gptr_kernel(
        const int* __restrict__ cnt,
        int* __restrict__ bucket_base, int* __restrict__ cursor,
        int* __restrict__ rowptr,
        const int* __restrict__ batch, int* __restrict__ gptr,
        int N, int E, int NG) {
    if (blockIdx.x == 0) {
        __shared__ int sc[256];
        int t = threadIdx.x;
        int c = (t < NBUCK) ? cnt[t] : 0;
        sc[t] = c;
        __syncthreads();
        for (int off = 1; off < 256; off <<= 1) {
            int v = (t >= off) ? sc[t - off] : 0;
            __syncthreads();
            sc[t] += v;
            __syncthreads();
        }
        if (t < NBUCK) { bucket_base[t] = sc[t] - c; cursor[t] = sc[t] - c; }
        if (t == NBUCK - 1) bucket_base[NBUCK] = sc[t];
        if (t == 0) rowptr[N] = E;
    } else {
        for (int g = threadIdx.x; g <= NG; g += 256) {
            if (g == NG) { gptr[NG] = N; continue; }
            int lo = 0, hi = N;
            while (lo < hi) {
                int mid = (lo + hi) >> 1;
                if (batch[mid] < g) lo = mid + 1; else hi = mid;
            }
            gptr[g] = lo;
        }
    }
}

// ---------- pass 3: bin edges into bucket regions ----------
__global__ __launch_bounds__(256) void bin_kernel(
        const int* __restrict__ src, const int* __restrict__ dst,
        int* __restrict__ cursor, unsigned int* __restrict__ pairs, int E) {
    __shared__ unsigned int stage[CHUNK];                 // 16 KB
    __shared__ int hist[256], sc[256], lbase[256], lcur[256], gbase[256];
    int tid = threadIdx.x;
    int e0 = blockIdx.x * CHUNK;
    int total = min(CHUNK, E - e0);
    hist[tid] = 0;
    __syncthreads();
    for (int i = tid; i < total; i += 256)
        atomicAdd(&hist[dst[e0 + i] >> BSHIFT], 1);
    __syncthreads();
    sc[tid] = hist[tid];
    __syncthreads();
    for (int off = 1; off < 256; off <<= 1) {
        int v = (tid >= off) ? sc[tid - off] : 0;
        __syncthreads();
        sc[tid] += v;
        __syncthreads();
    }
    lbase[tid] = sc[tid] - hist[tid];
    lcur[tid]  = sc[tid] - hist[tid];
    if (tid < NBUCK && hist[tid] > 0) gbase[tid] = atomicAdd(&cursor[tid], hist[tid]);
    __syncthreads();
    for (int i = tid; i < total; i += 256) {
        unsigned int s = (unsigned int)src[e0 + i];
        unsigned int d = (unsigned int)dst[e0 + i];
        int pos = atomicAdd(&lcur[d >> BSHIFT], 1);
        stage[pos] = (d << 16) | s;
    }
    __syncthreads();
    for (int i = tid; i < total; i += 256) {
        unsigned int p = stage[i];
        int b = (int)(p >> 24);
        pairs[gbase[b] + (i - lbase[b])] = p;
    }
}

// ---------- pass 4: counting sort -> csr(ushort), rowptr, dinv, deg ----------
// deghist updated via per-block LDS histogram -> ~60 low-contention global
// atomics per block (NOT per-node: hot degree bin would serialize ~4000 deep).
__global__ __launch_bounds__(256) void bucket_sort_kernel(
        const unsigned int* __restrict__ pairs, const int* __restrict__ base,
        unsigned short* __restrict__ csr, int* __restrict__ rowptr,
        float* __restrict__ dinv, unsigned char* __restrict__ deg,
        int* __restrict__ deghist, int N) {
    __shared__ int cntl[256], sc[256], cur[256], dh[256];
    int tid = threadIdx.x;
    int b = blockIdx.x;
    int pbase = base[b], pend = base[b + 1];
    int cnt = pend - pbase;
    cntl[tid] = 0;
    dh[tid] = 0;
    __syncthreads();
    for (int i = tid; i < cnt; i += 256)
        atomicAdd(&cntl[(pairs[pbase + i] >> 16) & 255u], 1);
    __syncthreads();
    sc[tid] = cntl[tid];
    __syncthreads();
    for (int off = 1; off < 256; off <<= 1) {
        int v = (tid >= off) ? sc[tid - off] : 0;
        __syncthreads();
        sc[tid] += v;
        __syncthreads();
    }
    int excl = sc[tid] - cntl[tid];
    cur[tid] = excl;
    int v = (b << BSHIFT) + tid;
    int d = min(cntl[tid], 255);
    if (v < N) {
        rowptr[v] = pbase + excl;
        dinv[v] = rsqrtf((float)(cntl[tid] + 1));  // deg = indeg + 1 (self loop)
        deg[v] = (unsigned char)d;
        atomicAdd(&dh[d], 1);                      // LDS, ~20-way max
    }
    __syncthreads();
    if (dh[tid]) atomicAdd(&deghist[tid], dh[tid]);  // <=196-way per address
    for (int i = tid; i < cnt; i += 256) {
        unsigned int p = pairs[pbase + i];
        int pos = atomicAdd(&cur[(p >> 16) & 255u], 1);
        csr[pbase + pos] = (unsigned short)(p & 0xffffu);
    }
}

// ---------- degree-bin exclusive scan (1 block) ----------
__global__ __launch_bounds__(256) void deg_scan_kernel(
        const int* __restrict__ deghist, int* __restrict__ degcur) {
    __shared__ int sc[256];
    int t = threadIdx.x;
    int c = deghist[t];
    sc[t] = c;
    __syncthreads();
    for (int off = 1; off < 256; off <<= 1) {
        int v = (t >= off) ? sc[t - off] : 0;
        __syncthreads();
        sc[t] += v;
        __syncthreads();
    }
    degcur[t] = sc[t] - c;  // exclusive
}

// ---------- build degree-grouped node permutation (two-level, low contention) ----------
__global__ __launch_bounds__(256) void perm_build_kernel(
        const unsigned char* __restrict__ deg, int* __restrict__ degcur,
        int* __restrict__ perm, int N) {
    __shared__ int dh[256], gbase[256], lcur[256];
    int tid = threadIdx.x;
    int v = (blockIdx.x << 8) + tid;
    dh[tid] = 0;
    lcur[tid] = 0;
    __syncthreads();
    int d = (v < N) ? (int)deg[v] : 0;
    if (v < N) atomicAdd(&dh[d], 1);               // LDS
    __syncthreads();
    if (dh[tid]) gbase[tid] = atomicAdd(&degcur[tid], dh[tid]);  // <=196-way
    __syncthreads();
    if (v < N) {
        int r = atomicAdd(&lcur[d], 1);            // LDS local rank
        perm[gbase[d] + r] = v;
    }
}

// ---------- gather aggregation (degree-grouped order, 2-edge pipeline) ----------
template <bool PRESCALED, bool F32OUT>
__global__ __launch_bounds__(256) void aggregate_kernel(
        const unsigned short* __restrict__ G, const int* __restrict__ rowptr,
        const unsigned short* __restrict__ csr, const float* __restrict__ dinv,
        const int* __restrict__ perm,
        void* __restrict__ Out, int N, int E, int relu) {
    int lane = threadIdx.x & 63;
    int w = (blockIdx.x * 256 + threadIdx.x) >> 6;
    int grp = lane >> 3, cl = lane & 7;
    int idx = w * 8 + grp;
    bool valid = idx < N;
    int v = perm[valid ? idx : N - 1];
    int beg = rowptr[v];
    int cnt = valid ? rowptr[v + 1] - beg : 0;
    int mx = cnt;
    mx = max(mx, __shfl_xor(mx, 8));
    mx = max(mx, __shfl_xor(mx, 16));
    mx = max(mx, __shfl_xor(mx, 32));

    const uint4* __restrict__ G4 = (const uint4*)G;
    float a0 = 0.f, a1 = 0.f, a2 = 0.f, a3 = 0.f;
    float a4 = 0.f, a5 = 0.f, a6 = 0.f, a7 = 0.f;
    float b0 = 0.f, b1 = 0.f, b2 = 0.f, b3 = 0.f;
    float b4 = 0.f, b5 = 0.f, b6 = 0.f, b7 = 0.f;
    int nit = (mx + 1) >> 1;
    for (int it = 0; it < nit; ++it) {
        int i0 = 2 * it, i1 = i0 + 1;
        int e0 = min(beg + i0, E - 1);
        int e1 = min(beg + i1, E - 1);
        bool ok0 = i0 < cnt, ok1 = i1 < cnt;
        int u0 = ok0 ? (int)csr[e0] : 0;
        int u1 = ok1 ? (int)csr[e1] : 0;
        float s0, s1;
        if (PRESCALED) { s0 = ok0 ? 1.f : 0.f;        s1 = ok1 ? 1.f : 0.f; }
        else           { s0 = ok0 ? dinv[u0] : 0.f;   s1 = ok1 ? dinv[u1] : 0.f; }
        uint4 q0 = G4[(size_t)u0 * 8 + cl];
        uint4 q1 = G4[(size_t)u1 * 8 + cl];
        a0 = fmaf(bf_lo(q0.x), s0, a0); a1 = fmaf(bf_hi(q0.x), s0, a1);
        a2 = fmaf(bf_lo(q0.y), s0, a2); a3 = fmaf(bf_hi(q0.y), s0, a3);
        a4 = fmaf(bf_lo(q0.z), s0, a4); a5 = fmaf(bf_hi(q0.z), s0, a5);
        a6 = fmaf(bf_lo(q0.w), s0, a6); a7 = fmaf(bf_hi(q0.w), s0, a7);
        b0 = fmaf(bf_lo(q1.x), s1, b0); b1 = fmaf(bf_hi(q1.x), s1, b1);
        b2 = fmaf(bf_lo(q1.y), s1, b2); b3 = fmaf(bf_hi(q1.y), s1, b3);
        b4 = fmaf(bf_lo(q1.z), s1, b4); b5 = fmaf(bf_hi(q1.z), s1, b5);
        b6 = fmaf(bf_lo(q1.w), s1, b6); b7 = fmaf(bf_hi(q1.w), s1, b7);
    }
    a0 += b0; a1 += b1; a2 += b2; a3 += b3;
    a4 += b4; a5 += b5; a6 += b6; a7 += b7;
    if (valid) {
        uint4 q = G4[(size_t)v * 8 + cl];   // self-loop term
        float d = dinv[v];
        float sv = PRESCALED ? 1.f : d;
        float o0 = (a0 + bf_lo(q.x) * sv) * d, o1 = (a1 + bf_hi(q.x) * sv) * d;
        float o2 = (a2 + bf_lo(q.y) * sv) * d, o3 = (a3 + bf_hi(q.y) * sv) * d;
        float o4 = (a4 + bf_lo(q.z) * sv) * d, o5 = (a5 + bf_hi(q.z) * sv) * d;
        float o6 = (a6 + bf_lo(q.w) * sv) * d, o7 = (a7 + bf_hi(q.w) * sv) * d;
        if (relu) {
            o0 = fmaxf(o0, 0.f); o1 = fmaxf(o1, 0.f); o2 = fmaxf(o2, 0.f);
            o3 = fmaxf(o3, 0.f); o4 = fmaxf(o4, 0.f); o5 = fmaxf(o5, 0.f);
            o6 = fmaxf(o6, 0.f); o7 = fmaxf(o7, 0.f);
        }
        if (F32OUT) {
            float4 w0 = {o0, o1, o2, o3}, w1 = {o4, o5, o6, o7};
            ((float4*)Out)[(size_t)v * 16 + cl * 2]     = w0;
            ((float4*)Out)[(size_t)v * 16 + cl * 2 + 1] = w1;
        } else {
            uint4 p;
            p.x = pack2bf(o0, o1); p.y = pack2bf(o2, o3);
            p.z = pack2bf(o4, o5); p.w = pack2bf(o6, o7);
            ((uint4*)Out)[(size_t)v * 8 + cl] = p;
        }
    }
}

// ---------- GEMM (bf16 input, K=64) + dinv prescale -> bf16 ----------
__global__ __launch_bounds__(256) void gemm_bf16_kernel(
        const unsigned short* __restrict__ Xbf, const float* __restrict__ W,
        const float* __restrict__ dinv, unsigned short* __restrict__ G, int N) {
    constexpr int XLDU = 36;
    __shared__ unsigned int Xs[64 * XLDU];  // 9216 B
    __shared__ float Wls[64 * CH];          // 16384 B
    int tid = threadIdx.x;
    int tx  = tid & 15;
    int ty  = tid >> 4;
    int row_tile = blockIdx.x * 64;
    int r0 = ty * 4;
    float acc[4][4] = {{0.f}};

#pragma unroll
    for (int t = 0; t < 2; ++t) {
        int idx = tid + t * 256;
        int row = idx >> 3;
        int k4  = idx & 7;
        int grow = row_tile + row;
        uint4 v = ((const uint4*)Xbf)[(size_t)min(grow, N - 1) * 8 + k4];
        *(uint4*)&Xs[row * XLDU + 4 * k4] = v;
    }
#pragma unroll
    for (int t = 0; t < 4; ++t) {
        int idx = tid + t * 256;
        *(float4*)&Wls[idx * 4] = ((const float4*)W)[idx];
    }
    __syncthreads();
#pragma unroll
    for (int kk = 0; kk < 64; kk += 4) {
        float xr[4][4], wr[4][4];
#pragma unroll
        for (int i = 0; i < 4; ++i) {
            uint2 q = *(const uint2*)&Xs[(r0 + i) * XLDU + (kk >> 1)];
            xr[i][0] = bf_lo(q.x); xr[i][1] = bf_hi(q.x);
            xr[i][2] = bf_lo(q.y); xr[i][3] = bf_hi(q.y);
        }
#pragma unroll
        for (int j = 0; j < 4; ++j) {
            float4 v = *(const float4*)&Wls[(kk + j) * CH + 4 * tx];
            wr[j][0] = v.x; wr[j][1] = v.y; wr[j][2] = v.z; wr[j][3] = v.w;
        }
#pragma unroll
        for (int i = 0; i < 4; ++i)
#pragma unroll
            for (int j = 0; j < 4; ++j)
#pragma unroll
                for (int c = 0; c < 4; ++c)
                    acc[i][c] = fmaf(xr[i][j], wr[j][c], acc[i][c]);
    }
#pragma unroll
    for (int i = 0; i < 4; ++i) {
        int r = row_tile + r0 + i;
        if (r < N) {
            float d = dinv[r];
            ushort4 o;
            o.x = f2bf_rne(acc[i][0] * d);
            o.y = f2bf_rne(acc[i][1] * d);
            o.z = f2bf_rne(acc[i][2] * d);
            o.w = f2bf_rne(acc[i][3] * d);
            ((ushort4*)G)[(size_t)r * 16 + tx] = o;
        }
    }
}

// ---------- fused mean-pool + linear head ----------
__global__ __launch_bounds__(64) void pool_head_kernel(
        const float* __restrict__ H, const int* __restrict__ gptr,
        const float* __restrict__ Wl, const float* __restrict__ bl,
        float* __restrict__ out, int NG) {
    int g = blockIdx.x;
    int lane = threadIdx.x;  // 64 = CH
    int s = gptr[g], e = gptr[g + 1];
    float acc = 0.f;
    for (int v = s; v < e; ++v) acc += H[(size_t)v * CH + lane];
    float c = (float)(e - s);
    float mean = (c > 0.f) ? acc / c : 0.f;
    for (int o = 0; o < 10; ++o) {
        float t = mean * Wl[lane * 10 + o];
        for (int off = 32; off > 0; off >>= 1) t += __shfl_down(t, off);
        if (lane == 0) out[g * 10 + o] = t + bl[o];
    }
}

extern "C" void kernel_launch(void* const* d_in, const int* in_sizes, int n_in,
                              void* d_out, int out_size, void* d_ws, size_t ws_size,
                              hipStream_t stream) {
    const float* x     = (const float*)d_in[0];
    const int*   ei    = (const int*)d_in[1];
    const int*   batch = (const int*)d_in[2];
    const float* W1    = (const float*)d_in[3];
    const float* W2    = (const float*)d_in[4];
    const float* W3    = (const float*)d_in[5];
    const float* Wl    = (const float*)d_in[6];
    const float* bl    = (const float*)d_in[7];
    float* out = (float*)d_out;

    const int N  = in_sizes[0] / 128;  // 50000 (< 65536)
    const int E  = in_sizes[1] / 2;    // 1250000
    const int NG = out_size / 10;      // 500

    const int* src = ei;
    const int* dst = ei + E;

    const int cb = (E + CHUNK - 1) / CHUNK;  // 306

    // workspace carve-out (256B aligned)
    char* ws = (char*)d_ws;
    size_t off = 0;
    auto alloc = [&](size_t bytes) -> void* {
        void* p = ws + off;
        off += bytes;
        off = (off + 255) & ~(size_t)255;
        return p;
    };
    int*   bucket_cnt  = (int*)alloc((size_t)NBUCK * 4);     // padded to 1024B
    int*   deghist     = (int*)alloc(256 * 4);               // adjacent: one memset
    int*   bucket_base = (int*)alloc((size_t)(NBUCK + 1) * 4);
    int*   cursor      = (int*)alloc((size_t)NBUCK * 4);
    int*   degcur      = (int*)alloc(256 * 4);
    unsigned short* csr = (unsigned short*)alloc((size_t)(E + 64) * 2);
    int*   rowptr = (int*)alloc((size_t)(N + 1) * 4);
    float* dinv   = (float*)alloc((size_t)N * 4);
    unsigned char* deg = (unsigned char*)alloc((size_t)N);
    int*   perm   = (int*)alloc((size_t)N * 4);
    int*   gptrb  = (int*)alloc((size_t)(NG + 1) * 4);
    unsigned short* GA = (unsigned short*)alloc((size_t)N * CH * 2);  // 6.4MB
    unsigned short* GB = (unsigned short*)alloc((size_t)N * CH * 2);  // 6.4MB
    float* hbuf   = (float*)alloc((size_t)N * CH * 4);   // 12.8MB; aliases pairs (5MB)
    unsigned int* pairs = (unsigned int*)hbuf;  // sort consumes before agg3 writes hbuf

    // zero bucket_cnt (1024B incl. pad) + deghist (1024B) in one memset
    hipMemsetAsync(bucket_cnt, 0, 2048, stream);

    int gb = (N + 63) / 64;            // 782 gemm tiles
    int ab = ((N + 7) / 8 + 3) / 4;    // agg: 8 nodes/wave, 4 waves/block
    int nb = (N + 255) / 256;          // 196

    // K0: gemm1 (raw messages) + histogram chunks in one launch
    gemm1_hist_kernel<128><<<gb + cb, 256, 0, stream>>>(x, W1, GA, N,
                                                        dst, bucket_cnt, E, gb);
    scan_gptr_kernel<<<2, 256, 0, stream>>>(bucket_cnt, bucket_base, cursor,
                                            rowptr, batch, gptrb, N, E, NG);
    bin_kernel<<<cb, 256, 0, stream>>>(src, dst, cursor, pairs, E);
    bucket_sort_kernel<<<NBUCK, 256, 0, stream>>>(pairs, bucket_base, csr, rowptr,
                                                  dinv, deg, deghist, N);
    deg_scan_kernel<<<1, 256, 0, stream>>>(deghist, degcur);
    perm_build_kernel<<<nb, 256, 0, stream>>>(deg, degcur, perm, N);

    // layer 1 aggregate (messages NOT prescaled -> multiply dinv[u] per edge)
    aggregate_kernel<false, false><<<ab, 256, 0, stream>>>(GA, rowptr, csr, dinv,
                                                           perm, GB, N, E, 1);
    // layer 2
    gemm_bf16_kernel<<<gb, 256, 0, stream>>>(GB, W2, dinv, GA, N);
    aggregate_kernel<true, false><<<ab, 256, 0, stream>>>(GA, rowptr, csr, dinv,
                                                          perm, GB, N, E, 1);
    // layer 3
    gemm_bf16_kernel<<<gb, 256, 0, stream>>>(GB, W3, dinv, GA, N);
    aggregate_kernel<true, true><<<ab, 256, 0, stream>>>(GA, rowptr, csr, dinv,
                                                         perm, hbuf, N, E, 0);

    // mean pool + linear head
    pool_head_kernel<<<NG, 64, 0, stream>>>(hbuf, gptrb, Wl, bl, out, NG);
}

// Round 13
// 238.658 us; speedup vs baseline: 2.1549x; 1.1056x over previous
//
#include <hip/hip_runtime.h>

#define CH 64
#define CHUNK 4096
#define BSHIFT 8          // 256 nodes per bucket
#define NBUCK 196         // ceil(50000 / 256); requires N < 65536 (16-bit packing)

__device__ __forceinline__ unsigned short f2bf_rne(float f) {
    unsigned int u = __float_as_uint(f);
    u += 0x7fffu + ((u >> 16) & 1u);   // round to nearest even
    return (unsigned short)(u >> 16);
}
__device__ __forceinline__ float bf_lo(unsigned int q) {
    return __uint_as_float(q << 16);
}
__device__ __forceinline__ float bf_hi(unsigned int q) {
    return __uint_as_float(q & 0xffff0000u);
}
__device__ __forceinline__ unsigned int pack2bf(float lo, float hi) {
    return (unsigned int)f2bf_rne(lo) | ((unsigned int)f2bf_rne(hi) << 16);
}

// ---------- K0: layer-1 GEMM (raw messages, no dinv) + global bucket histogram ----------
template <int K>
__global__ __launch_bounds__(256) void gemm1_hist_kernel(
        const float* __restrict__ X, const float* __restrict__ W,
        unsigned short* __restrict__ G, int N,
        const int* __restrict__ dst, int* __restrict__ bucket_cnt, int E,
        int gemm_blocks) {
    constexpr int KC  = 64;
    constexpr int XLD = KC + 4;
    __shared__ float Xs[64 * XLD];        // 17408 B
    __shared__ float Wls[KC * CH];        // 16384 B
    __shared__ int hist[256];             // 1024 B
    int tid = threadIdx.x;

    if (blockIdx.x >= gemm_blocks) {
        int cid = blockIdx.x - gemm_blocks;
        int e0 = cid * CHUNK;
        int total = min(CHUNK, E - e0);
        hist[tid] = 0;
        __syncthreads();
        for (int i = tid; i < total; i += 256)
            atomicAdd(&hist[dst[e0 + i] >> BSHIFT], 1);
        __syncthreads();
        if (tid < NBUCK && hist[tid]) atomicAdd(&bucket_cnt[tid], hist[tid]);
        return;
    }

    // ---- gemm part: G = bf16(X @ W) ----
    int tx  = tid & 15;
    int ty  = tid >> 4;
    int row_tile = blockIdx.x * 64;
    int r0 = ty * 4;
    float acc[4][4] = {{0.f}};

    for (int kc = 0; kc < K; kc += KC) {
        __syncthreads();
#pragma unroll
        for (int t = 0; t < 4; ++t) {
            int idx = tid + t * 256;
            int row = idx >> 4;
            int k4  = idx & 15;
            int grow = row_tile + row;
            const float4* xs = (const float4*)(X + (size_t)min(grow, N - 1) * K + kc);
            *(float4*)&Xs[row * XLD + 4 * k4] = xs[k4];
        }
#pragma unroll
        for (int t = 0; t < 4; ++t) {
            int idx = tid + t * 256;
            *(float4*)&Wls[idx * 4] = ((const float4*)(W + (size_t)kc * CH))[idx];
        }
        __syncthreads();
#pragma unroll
        for (int kk = 0; kk < KC; kk += 4) {
            float xr[4][4], wr[4][4];
#pragma unroll
            for (int i = 0; i < 4; ++i) {
                float4 v = *(const float4*)&Xs[(r0 + i) * XLD + kk];
                xr[i][0] = v.x; xr[i][1] = v.y; xr[i][2] = v.z; xr[i][3] = v.w;
            }
#pragma unroll
            for (int j = 0; j < 4; ++j) {
                float4 v = *(const float4*)&Wls[(kk + j) * CH + 4 * tx];
                wr[j][0] = v.x; wr[j][1] = v.y; wr[j][2] = v.z; wr[j][3] = v.w;
            }
#pragma unroll
            for (int i = 0; i < 4; ++i)
#pragma unroll
                for (int j = 0; j < 4; ++j)
#pragma unroll
                    for (int c = 0; c < 4; ++c)
                        acc[i][c] = fmaf(xr[i][j], wr[j][c], acc[i][c]);
        }
    }
#pragma unroll
    for (int i = 0; i < 4; ++i) {
        int r = row_tile + r0 + i;
        if (r < N) {
            ushort4 o;
            o.x = f2bf_rne(acc[i][0]);
            o.y = f2bf_rne(acc[i][1]);
            o.z = f2bf_rne(acc[i][2]);
            o.w = f2bf_rne(acc[i][3]);
            ((ushort4*)G)[(size_t)r * 16 + tx] = o;
        }
    }
}

// ---------- pass 2: block 0: 196-entry scan -> base+cursor; block 1: gptr ----------
__global__ __launch_bounds__(256) void scan_gptr_kernel(
        const int* __restrict__ cnt,
        int* __restrict__ bucket_base, int* __restrict__ cursor,
        int* __restrict__ rowptr,
        const int* __restrict__ batch, int* __restrict__ gptr,
        int N, int E, int NG) {
    if (blockIdx.x == 0) {
        __shared__ int sc[256];
        int t = threadIdx.x;
        int c = (t < NBUCK) ? cnt[t] : 0;
        sc[t] = c;
        __syncthreads();
        for (int off = 1; off < 256; off <<= 1) {
            int v = (t >= off) ? sc[t - off] : 0;
            __syncthreads();
            sc[t] += v;
            __syncthreads();
        }
        if (t < NBUCK) { bucket_base[t] = sc[t] - c; cursor[t] = sc[t] - c; }
        if (t == NBUCK - 1) bucket_base[NBUCK] = sc[t];
        if (t == 0) rowptr[N] = E;
    } else {
        for (int g = threadIdx.x; g <= NG; g += 256) {
            if (g == NG) { gptr[NG] = N; continue; }
            int lo = 0, hi = N;
            while (lo < hi) {
                int mid = (lo + hi) >> 1;
                if (batch[mid] < g) lo = mid + 1; else hi = mid;
            }
            gptr[g] = lo;
        }
    }
}

// ---------- pass 3: bin edges into bucket regions ----------
__global__ __launch_bounds__(256) void bin_kernel(
        const int* __restrict__ src, const int* __restrict__ dst,
        int* __restrict__ cursor, unsigned int* __restrict__ pairs, int E) {
    __shared__ unsigned int stage[CHUNK];                 // 16 KB
    __shared__ int hist[256], sc[256], lbase[256], lcur[256], gbase[256];
    int tid = threadIdx.x;
    int e0 = blockIdx.x * CHUNK;
    int total = min(CHUNK, E - e0);
    hist[tid] = 0;
    __syncthreads();
    for (int i = tid; i < total; i += 256)
        atomicAdd(&hist[dst[e0 + i] >> BSHIFT], 1);
    __syncthreads();
    sc[tid] = hist[tid];
    __syncthreads();
    for (int off = 1; off < 256; off <<= 1) {
        int v = (tid >= off) ? sc[tid - off] : 0;
        __syncthreads();
        sc[tid] += v;
        __syncthreads();
    }
    lbase[tid] = sc[tid] - hist[tid];
    lcur[tid]  = sc[tid] - hist[tid];
    if (tid < NBUCK && hist[tid] > 0) gbase[tid] = atomicAdd(&cursor[tid], hist[tid]);
    __syncthreads();
    for (int i = tid; i < total; i += 256) {
        unsigned int s = (unsigned int)src[e0 + i];
        unsigned int d = (unsigned int)dst[e0 + i];
        int pos = atomicAdd(&lcur[d >> BSHIFT], 1);
        stage[pos] = (d << 16) | s;
    }
    __syncthreads();
    for (int i = tid; i < total; i += 256) {
        unsigned int p = stage[i];
        int b = (int)(p >> 24);
        pairs[gbase[b] + (i - lbase[b])] = p;
    }
}

// ---------- pass 4: per-bucket counting sort -> csr(ushort), rowptr, dinv ----------
__global__ __launch_bounds__(256) void bucket_sort_kernel(
        const unsigned int* __restrict__ pairs, const int* __restrict__ base,
        unsigned short* __restrict__ csr, int* __restrict__ rowptr,
        float* __restrict__ dinv, int N) {
    __shared__ int cntl[256], sc[256], cur[256];
    int tid = threadIdx.x;
    int b = blockIdx.x;
    int pbase = base[b], pend = base[b + 1];
    int cnt = pend - pbase;
    cntl[tid] = 0;
    __syncthreads();
    for (int i = tid; i < cnt; i += 256)
        atomicAdd(&cntl[(pairs[pbase + i] >> 16) & 255u], 1);
    __syncthreads();
    sc[tid] = cntl[tid];
    __syncthreads();
    for (int off = 1; off < 256; off <<= 1) {
        int v = (tid >= off) ? sc[tid - off] : 0;
        __syncthreads();
        sc[tid] += v;
        __syncthreads();
    }
    int excl = sc[tid] - cntl[tid];
    cur[tid] = excl;
    int v = (b << BSHIFT) + tid;
    if (v < N) {
        rowptr[v] = pbase + excl;
        dinv[v] = rsqrtf((float)(cntl[tid] + 1));  // deg = indeg + 1 (self loop)
    }
    __syncthreads();
    for (int i = tid; i < cnt; i += 256) {
        unsigned int p = pairs[pbase + i];
        int pos = atomicAdd(&cur[(p >> 16) & 255u], 1);
        csr[pbase + pos] = (unsigned short)(p & 0xffffu);
    }
}

// ---------- gather aggregation (natural order, 2-edge pipeline, unroll 2) ----------
// 8 nodes/wave, 8 lanes/node (uint4 = 8 bf16 channels). Writes fully coalesced.
template <bool PRESCALED, bool F32OUT>
__global__ __launch_bounds__(256) void aggregate_kernel(
        const unsigned short* __restrict__ G, const int* __restrict__ rowptr,
        const unsigned short* __restrict__ csr, const float* __restrict__ dinv,
        void* __restrict__ Out, int N, int E, int relu) {
    int lane = threadIdx.x & 63;
    int w = (blockIdx.x * 256 + threadIdx.x) >> 6;
    int grp = lane >> 3, cl = lane & 7;
    int v = w * 8 + grp;
    bool valid = v < N;
    int vc = valid ? v : N - 1;
    int beg = rowptr[vc];
    int cnt = valid ? rowptr[vc + 1] - beg : 0;
    int mx = cnt;
    mx = max(mx, __shfl_xor(mx, 8));
    mx = max(mx, __shfl_xor(mx, 16));
    mx = max(mx, __shfl_xor(mx, 32));

    const uint4* __restrict__ G4 = (const uint4*)G;
    float a0 = 0.f, a1 = 0.f, a2 = 0.f, a3 = 0.f;
    float a4 = 0.f, a5 = 0.f, a6 = 0.f, a7 = 0.f;
    float b0 = 0.f, b1 = 0.f, b2 = 0.f, b3 = 0.f;
    float b4 = 0.f, b5 = 0.f, b6 = 0.f, b7 = 0.f;
    int nit = (mx + 1) >> 1;
#pragma unroll 2
    for (int it = 0; it < nit; ++it) {
        int i0 = 2 * it, i1 = i0 + 1;
        int e0 = min(beg + i0, E - 1);
        int e1 = min(beg + i1, E - 1);
        bool ok0 = i0 < cnt, ok1 = i1 < cnt;
        int u0 = ok0 ? (int)csr[e0] : 0;
        int u1 = ok1 ? (int)csr[e1] : 0;
        float s0, s1;
        if (PRESCALED) { s0 = ok0 ? 1.f : 0.f;        s1 = ok1 ? 1.f : 0.f; }
        else           { s0 = ok0 ? dinv[u0] : 0.f;   s1 = ok1 ? dinv[u1] : 0.f; }
        uint4 q0 = G4[(size_t)u0 * 8 + cl];
        uint4 q1 = G4[(size_t)u1 * 8 + cl];
        a0 = fmaf(bf_lo(q0.x), s0, a0); a1 = fmaf(bf_hi(q0.x), s0, a1);
        a2 = fmaf(bf_lo(q0.y), s0, a2); a3 = fmaf(bf_hi(q0.y), s0, a3);
        a4 = fmaf(bf_lo(q0.z), s0, a4); a5 = fmaf(bf_hi(q0.z), s0, a5);
        a6 = fmaf(bf_lo(q0.w), s0, a6); a7 = fmaf(bf_hi(q0.w), s0, a7);
        b0 = fmaf(bf_lo(q1.x), s1, b0); b1 = fmaf(bf_hi(q1.x), s1, b1);
        b2 = fmaf(bf_lo(q1.y), s1, b2); b3 = fmaf(bf_hi(q1.y), s1, b3);
        b4 = fmaf(bf_lo(q1.z), s1, b4); b5 = fmaf(bf_hi(q1.z), s1, b5);
        b6 = fmaf(bf_lo(q1.w), s1, b6); b7 = fmaf(bf_hi(q1.w), s1, b7);
    }
    a0 += b0; a1 += b1; a2 += b2; a3 += b3;
    a4 += b4; a5 += b5; a6 += b6; a7 += b7;
    if (valid) {
        uint4 q = G4[(size_t)v * 8 + cl];   // self-loop term
        float d = dinv[v];
        float sv = PRESCALED ? 1.f : d;
        float o0 = (a0 + bf_lo(q.x) * sv) * d, o1 = (a1 + bf_hi(q.x) * sv) * d;
        float o2 = (a2 + bf_lo(q.y) * sv) * d, o3 = (a3 + bf_hi(q.y) * sv) * d;
        float o4 = (a4 + bf_lo(q.z) * sv) * d, o5 = (a5 + bf_hi(q.z) * sv) * d;
        float o6 = (a6 + bf_lo(q.w) * sv) * d, o7 = (a7 + bf_hi(q.w) * sv) * d;
        if (relu) {
            o0 = fmaxf(o0, 0.f); o1 = fmaxf(o1, 0.f); o2 = fmaxf(o2, 0.f);
            o3 = fmaxf(o3, 0.f); o4 = fmaxf(o4, 0.f); o5 = fmaxf(o5, 0.f);
            o6 = fmaxf(o6, 0.f); o7 = fmaxf(o7, 0.f);
        }
        if (F32OUT) {
            float4 w0 = {o0, o1, o2, o3}, w1 = {o4, o5, o6, o7};
            ((float4*)Out)[(size_t)v * 16 + cl * 2]     = w0;
            ((float4*)Out)[(size_t)v * 16 + cl * 2 + 1] = w1;
        } else {
            uint4 p;
            p.x = pack2bf(o0, o1); p.y = pack2bf(o2, o3);
            p.z = pack2bf(o4, o5); p.w = pack2bf(o6, o7);
            ((uint4*)Out)[(size_t)v * 8 + cl] = p;
        }
    }
}

// ---------- GEMM (bf16 input, K=64) + dinv prescale -> bf16 ----------
__global__ __launch_bounds__(256) void gemm_bf16_kernel(
        const unsigned short* __restrict__ Xbf, const float* __restrict__ W,
        const float* __restrict__ dinv, unsigned short* __restrict__ G, int N) {
    constexpr int XLDU = 36;
    __shared__ unsigned int Xs[64 * XLDU];  // 9216 B
    __shared__ float Wls[64 * CH];          // 16384 B
    int tid = threadIdx.x;
    int tx  = tid & 15;
    int ty  = tid >> 4;
    int row_tile = blockIdx.x * 64;
    int r0 = ty * 4;
    float acc[4][4] = {{0.f}};

#pragma unroll
    for (int t = 0; t < 2; ++t) {
        int idx = tid + t * 256;
        int row = idx >> 3;
        int k4  = idx & 7;
        int grow = row_tile + row;
        uint4 v = ((const uint4*)Xbf)[(size_t)min(grow, N - 1) * 8 + k4];
        *(uint4*)&Xs[row * XLDU + 4 * k4] = v;
    }
#pragma unroll
    for (int t = 0; t < 4; ++t) {
        int idx = tid + t * 256;
        *(float4*)&Wls[idx * 4] = ((const float4*)W)[idx];
    }
    __syncthreads();
#pragma unroll
    for (int kk = 0; kk < 64; kk += 4) {
        float xr[4][4], wr[4][4];
#pragma unroll
        for (int i = 0; i < 4; ++i) {
            uint2 q = *(const uint2*)&Xs[(r0 + i) * XLDU + (kk >> 1)];
            xr[i][0] = bf_lo(q.x); xr[i][1] = bf_hi(q.x);
            xr[i][2] = bf_lo(q.y); xr[i][3] = bf_hi(q.y);
        }
#pragma unroll
        for (int j = 0; j < 4; ++j) {
            float4 v = *(const float4*)&Wls[(kk + j) * CH + 4 * tx];
            wr[j][0] = v.x; wr[j][1] = v.y; wr[j][2] = v.z; wr[j][3] = v.w;
        }
#pragma unroll
        for (int i = 0; i < 4; ++i)
#pragma unroll
            for (int j = 0; j < 4; ++j)
#pragma unroll
                for (int c = 0; c < 4; ++c)
                    acc[i][c] = fmaf(xr[i][j], wr[j][c], acc[i][c]);
    }
#pragma unroll
    for (int i = 0; i < 4; ++i) {
        int r = row_tile + r0 + i;
        if (r < N) {
            float d = dinv[r];
            ushort4 o;
            o.x = f2bf_rne(acc[i][0] * d);
            o.y = f2bf_rne(acc[i][1] * d);
            o.z = f2bf_rne(acc[i][2] * d);
            o.w = f2bf_rne(acc[i][3] * d);
            ((ushort4*)G)[(size_t)r * 16 + tx] = o;
        }
    }
}

// ---------- fused mean-pool + linear head ----------
__global__ __launch_bounds__(64) void pool_head_kernel(
        const float* __restrict__ H, const int* __restrict__ gptr,
        const float* __restrict__ Wl, const float* __restrict__ bl,
        float* __restrict__ out, int NG) {
    int g = blockIdx.x;
    int lane = threadIdx.x;  // 64 = CH
    int s = gptr[g], e = gptr[g + 1];
    float acc = 0.f;
    for (int v = s; v < e; ++v) acc += H[(size_t)v * CH + lane];
    float c = (float)(e - s);
    float mean = (c > 0.f) ? acc / c : 0.f;
    for (int o = 0; o < 10; ++o) {
        float t = mean * Wl[lane * 10 + o];
        for (int off = 32; off > 0; off >>= 1) t += __shfl_down(t, off);
        if (lane == 0) out[g * 10 + o] = t + bl[o];
    }
}

extern "C" void kernel_launch(void* const* d_in, const int* in_sizes, int n_in,
                              void* d_out, int out_size, void* d_ws, size_t ws_size,
                              hipStream_t stream) {
    const float* x     = (const float*)d_in[0];
    const int*   ei    = (const int*)d_in[1];
    const int*   batch = (const int*)d_in[2];
    const float* W1    = (const float*)d_in[3];
    const float* W2    = (const float*)d_in[4];
    const float* W3    = (const float*)d_in[5];
    const float* Wl    = (const float*)d_in[6];
    const float* bl    = (const float*)d_in[7];
    float* out = (float*)d_out;

    const int N  = in_sizes[0] / 128;  // 50000 (< 65536)
    const int E  = in_sizes[1] / 2;    // 1250000
    const int NG = out_size / 10;      // 500

    const int* src = ei;
    const int* dst = ei + E;

    const int cb = (E + CHUNK - 1) / CHUNK;  // 306

    // workspace carve-out (256B aligned)
    char* ws = (char*)d_ws;
    size_t off = 0;
    auto alloc = [&](size_t bytes) -> void* {
        void* p = ws + off;
        off += bytes;
        off = (off + 255) & ~(size_t)255;
        return p;
    };
    int*   bucket_cnt  = (int*)alloc((size_t)NBUCK * 4);
    int*   bucket_base = (int*)alloc((size_t)(NBUCK + 1) * 4);
    int*   cursor      = (int*)alloc((size_t)NBUCK * 4);
    unsigned short* csr = (unsigned short*)alloc((size_t)(E + 64) * 2);
    int*   rowptr = (int*)alloc((size_t)(N + 1) * 4);
    float* dinv   = (float*)alloc((size_t)N * 4);
    int*   gptrb  = (int*)alloc((size_t)(NG + 1) * 4);
    unsigned short* GA = (unsigned short*)alloc((size_t)N * CH * 2);  // 6.4MB
    unsigned short* GB = (unsigned short*)alloc((size_t)N * CH * 2);  // 6.4MB
    float* hbuf   = (float*)alloc((size_t)N * CH * 4);   // 12.8MB; aliases pairs (5MB)
    unsigned int* pairs = (unsigned int*)hbuf;  // sort consumes before agg3 writes hbuf

    hipMemsetAsync(bucket_cnt, 0, (size_t)NBUCK * 4, stream);

    int gb = (N + 63) / 64;            // 782 gemm tiles
    int ab = ((N + 7) / 8 + 3) / 4;    // agg: 8 nodes/wave, 4 waves/block

    // K0: gemm1 (raw messages) + histogram chunks in one launch
    gemm1_hist_kernel<128><<<gb + cb, 256, 0, stream>>>(x, W1, GA, N,
                                                        dst, bucket_cnt, E, gb);
    scan_gptr_kernel<<<2, 256, 0, stream>>>(bucket_cnt, bucket_base, cursor,
                                            rowptr, batch, gptrb, N, E, NG);
    bin_kernel<<<cb, 256, 0, stream>>>(src, dst, cursor, pairs, E);
    bucket_sort_kernel<<<NBUCK, 256, 0, stream>>>(pairs, bucket_base, csr, rowptr, dinv, N);

    // layer 1 aggregate (messages NOT prescaled -> multiply dinv[u] per edge)
    aggregate_kernel<false, false><<<ab, 256, 0, stream>>>(GA, rowptr, csr, dinv,
                                                           GB, N, E, 1);
    // layer 2
    gemm_bf16_kernel<<<gb, 256, 0, stream>>>(GB, W2, dinv, GA, N);
    aggregate_kernel<true, false><<<ab, 256, 0, stream>>>(GA, rowptr, csr, dinv,
                                                          GB, N, E, 1);
    // layer 3
    gemm_bf16_kernel<<<gb, 256, 0, stream>>>(GB, W3, dinv, GA, N);
    aggregate_kernel<true, true><<<ab, 256, 0, stream>>>(GA, rowptr, csr, dinv,
                                                         hbuf, N, E, 0);

    // mean pool + linear head
    pool_head_kernel<<<NG, 64, 0, stream>>>(hbuf, gptrb, Wl, bl, out, NG);
}

// Round 14
// 238.209 us; speedup vs baseline: 2.1589x; 1.0019x over previous
//
#include <hip/hip_runtime.h>

#define CH 64
#define CHUNK 4096
#define BSHIFT 8          // 256 nodes per bucket
#define NBUCK 196         // ceil(50000 / 256); requires N < 65536 (16-bit packing)

__device__ __forceinline__ unsigned short f2bf_rne(float f) {
    unsigned int u = __float_as_uint(f);
    u += 0x7fffu + ((u >> 16) & 1u);   // round to nearest even
    return (unsigned short)(u >> 16);
}
__device__ __forceinline__ float bf_lo(unsigned int q) {
    return __uint_as_float(q << 16);
}
__device__ __forceinline__ float bf_hi(unsigned int q) {
    return __uint_as_float(q & 0xffff0000u);
}
__device__ __forceinline__ unsigned int pack2bf(float lo, float hi) {
    return (unsigned int)f2bf_rne(lo) | ((unsigned int)f2bf_rne(hi) << 16);
}

// ---------- pass 1: per-chunk LDS histogram -> global bucket_cnt ----------
__global__ __launch_bounds__(256) void hist_kernel(
        const int* __restrict__ dst, int* __restrict__ bucket_cnt, int E) {
    __shared__ int hist[256];
    int tid = threadIdx.x;
    int e0 = blockIdx.x * CHUNK;
    int total = min(CHUNK, E - e0);
    hist[tid] = 0;
    __syncthreads();
    for (int i = tid; i < total; i += 256)
        atomicAdd(&hist[dst[e0 + i] >> BSHIFT], 1);
    __syncthreads();
    if (tid < NBUCK && hist[tid]) atomicAdd(&bucket_cnt[tid], hist[tid]);
}

// ---------- pass 2: block 0: 196-entry scan -> base+cursor; block 1: gptr ----------
__global__ __launch_bounds__(256) void scan_gptr_kernel(
        const int* __restrict__ cnt,
        int* __restrict__ bucket_base, int* __restrict__ cursor,
        int* __restrict__ rowptr,
        const int* __restrict__ batch, int* __restrict__ gptr,
        int N, int E, int NG) {
    if (blockIdx.x == 0) {
        __shared__ int sc[256];
        int t = threadIdx.x;
        int c = (t < NBUCK) ? cnt[t] : 0;
        sc[t] = c;
        __syncthreads();
        for (int off = 1; off < 256; off <<= 1) {
            int v = (t >= off) ? sc[t - off] : 0;
            __syncthreads();
            sc[t] += v;
            __syncthreads();
        }
        if (t < NBUCK) { bucket_base[t] = sc[t] - c; cursor[t] = sc[t] - c; }
        if (t == NBUCK - 1) bucket_base[NBUCK] = sc[t];
        if (t == 0) rowptr[N] = E;
    } else {
        for (int g = threadIdx.x; g <= NG; g += 256) {
            if (g == NG) { gptr[NG] = N; continue; }
            int lo = 0, hi = N;
            while (lo < hi) {
                int mid = (lo + hi) >> 1;
                if (batch[mid] < g) lo = mid + 1; else hi = mid;
            }
            gptr[g] = lo;
        }
    }
}

// ---------- K1: layer-1 GEMM (raw messages) fused with bin (overlapped) ----------
// Blocks [0, gemm_blocks): 64x64 GEMM tile -> GA = bf16(X @ W1).
// Blocks [gemm_blocks, +cb): bin chunk -> pairs (bucket-segmented, coalesced).
// bin's LDS aliases the gemm tile buffers (block-uniform branch).
template <int K>
__global__ __launch_bounds__(256) void gemm1_bin_kernel(
        const float* __restrict__ X, const float* __restrict__ W,
        unsigned short* __restrict__ G, int N,
        const int* __restrict__ src, const int* __restrict__ dst,
        int* __restrict__ cursor, unsigned int* __restrict__ pairs, int E,
        int gemm_blocks) {
    constexpr int KC  = 64;
    constexpr int XLD = KC + 4;
    __shared__ float Xs[64 * XLD];        // 17408 B (bin: stage, 16384 B)
    __shared__ float Wls[KC * CH];        // 16384 B (bin: hist/sc/lbase/lcur/gbase, 5120 B)
    int tid = threadIdx.x;

    if (blockIdx.x >= gemm_blocks) {
        // ---- bin branch ----
        unsigned int* stage = (unsigned int*)Xs;          // [CHUNK] 16 KB
        int* hist  = (int*)Wls;                           // [256]
        int* sc    = hist + 256;
        int* lbase = hist + 512;
        int* lcur  = hist + 768;
        int* gbase = hist + 1024;
        int cid = blockIdx.x - gemm_blocks;
        int e0 = cid * CHUNK;
        int total = min(CHUNK, E - e0);
        hist[tid] = 0;
        __syncthreads();
        for (int i = tid; i < total; i += 256)
            atomicAdd(&hist[dst[e0 + i] >> BSHIFT], 1);
        __syncthreads();
        sc[tid] = hist[tid];
        __syncthreads();
        for (int off = 1; off < 256; off <<= 1) {
            int v = (tid >= off) ? sc[tid - off] : 0;
            __syncthreads();
            sc[tid] += v;
            __syncthreads();
        }
        lbase[tid] = sc[tid] - hist[tid];
        lcur[tid]  = sc[tid] - hist[tid];
        if (tid < NBUCK && hist[tid] > 0) gbase[tid] = atomicAdd(&cursor[tid], hist[tid]);
        __syncthreads();
        for (int i = tid; i < total; i += 256) {
            unsigned int s = (unsigned int)src[e0 + i];
            unsigned int d = (unsigned int)dst[e0 + i];
            int pos = atomicAdd(&lcur[d >> BSHIFT], 1);
            stage[pos] = (d << 16) | s;
        }
        __syncthreads();
        for (int i = tid; i < total; i += 256) {
            unsigned int p = stage[i];
            int b = (int)(p >> 24);
            pairs[gbase[b] + (i - lbase[b])] = p;
        }
        return;
    }

    // ---- gemm branch: G = bf16(X @ W) ----
    int tx  = tid & 15;
    int ty  = tid >> 4;
    int row_tile = blockIdx.x * 64;
    int r0 = ty * 4;
    float acc[4][4] = {{0.f}};

    for (int kc = 0; kc < K; kc += KC) {
        __syncthreads();
#pragma unroll
        for (int t = 0; t < 4; ++t) {
            int idx = tid + t * 256;
            int row = idx >> 4;
            int k4  = idx & 15;
            int grow = row_tile + row;
            const float4* xs = (const float4*)(X + (size_t)min(grow, N - 1) * K + kc);
            *(float4*)&Xs[row * XLD + 4 * k4] = xs[k4];
        }
#pragma unroll
        for (int t = 0; t < 4; ++t) {
            int idx = tid + t * 256;
            *(float4*)&Wls[idx * 4] = ((const float4*)(W + (size_t)kc * CH))[idx];
        }
        __syncthreads();
#pragma unroll
        for (int kk = 0; kk < KC; kk += 4) {
            float xr[4][4], wr[4][4];
#pragma unroll
            for (int i = 0; i < 4; ++i) {
                float4 v = *(const float4*)&Xs[(r0 + i) * XLD + kk];
                xr[i][0] = v.x; xr[i][1] = v.y; xr[i][2] = v.z; xr[i][3] = v.w;
            }
#pragma unroll
            for (int j = 0; j < 4; ++j) {
                float4 v = *(const float4*)&Wls[(kk + j) * CH + 4 * tx];
                wr[j][0] = v.x; wr[j][1] = v.y; wr[j][2] = v.z; wr[j][3] = v.w;
            }
#pragma unroll
            for (int i = 0; i < 4; ++i)
#pragma unroll
                for (int j = 0; j < 4; ++j)
#pragma unroll
                    for (int c = 0; c < 4; ++c)
                        acc[i][c] = fmaf(xr[i][j], wr[j][c], acc[i][c]);
        }
    }
#pragma unroll
    for (int i = 0; i < 4; ++i) {
        int r = row_tile + r0 + i;
        if (r < N) {
            ushort4 o;
            o.x = f2bf_rne(acc[i][0]);
            o.y = f2bf_rne(acc[i][1]);
            o.z = f2bf_rne(acc[i][2]);
            o.w = f2bf_rne(acc[i][3]);
            ((ushort4*)G)[(size_t)r * 16 + tx] = o;
        }
    }
}

// ---------- pass 4: per-bucket counting sort -> csr(ushort), rowptr, dinv ----------
__global__ __launch_bounds__(256) void bucket_sort_kernel(
        const unsigned int* __restrict__ pairs, const int* __restrict__ base,
        unsigned short* __restrict__ csr, int* __restrict__ rowptr,
        float* __restrict__ dinv, int N) {
    __shared__ int cntl[256], sc[256], cur[256];
    int tid = threadIdx.x;
    int b = blockIdx.x;
    int pbase = base[b], pend = base[b + 1];
    int cnt = pend - pbase;
    cntl[tid] = 0;
    __syncthreads();
    for (int i = tid; i < cnt; i += 256)
        atomicAdd(&cntl[(pairs[pbase + i] >> 16) & 255u], 1);
    __syncthreads();
    sc[tid] = cntl[tid];
    __syncthreads();
    for (int off = 1; off < 256; off <<= 1) {
        int v = (tid >= off) ? sc[tid - off] : 0;
        __syncthreads();
        sc[tid] += v;
        __syncthreads();
    }
    int excl = sc[tid] - cntl[tid];
    cur[tid] = excl;
    int v = (b << BSHIFT) + tid;
    if (v < N) {
        rowptr[v] = pbase + excl;
        dinv[v] = rsqrtf((float)(cntl[tid] + 1));  // deg = indeg + 1 (self loop)
    }
    __syncthreads();
    for (int i = tid; i < cnt; i += 256) {
        unsigned int p = pairs[pbase + i];
        int pos = atomicAdd(&cur[(p >> 16) & 255u], 1);
        csr[pbase + pos] = (unsigned short)(p & 0xffffu);
    }
}

// ---------- gather aggregation (natural order, 2-edge pipeline, unroll 2) ----------
// 8 nodes/wave, 8 lanes/node (uint4 = 8 bf16 channels). Writes fully coalesced.
template <bool PRESCALED, bool F32OUT>
__global__ __launch_bounds__(256) void aggregate_kernel(
        const unsigned short* __restrict__ G, const int* __restrict__ rowptr,
        const unsigned short* __restrict__ csr, const float* __restrict__ dinv,
        void* __restrict__ Out, int N, int E, int relu) {
    int lane = threadIdx.x & 63;
    int w = (blockIdx.x * 256 + threadIdx.x) >> 6;
    int grp = lane >> 3, cl = lane & 7;
    int v = w * 8 + grp;
    bool valid = v < N;
    int vc = valid ? v : N - 1;
    int beg = rowptr[vc];
    int cnt = valid ? rowptr[vc + 1] - beg : 0;
    int mx = cnt;
    mx = max(mx, __shfl_xor(mx, 8));
    mx = max(mx, __shfl_xor(mx, 16));
    mx = max(mx, __shfl_xor(mx, 32));

    const uint4* __restrict__ G4 = (const uint4*)G;
    float a0 = 0.f, a1 = 0.f, a2 = 0.f, a3 = 0.f;
    float a4 = 0.f, a5 = 0.f, a6 = 0.f, a7 = 0.f;
    float b0 = 0.f, b1 = 0.f, b2 = 0.f, b3 = 0.f;
    float b4 = 0.f, b5 = 0.f, b6 = 0.f, b7 = 0.f;
    int nit = (mx + 1) >> 1;
#pragma unroll 2
    for (int it = 0; it < nit; ++it) {
        int i0 = 2 * it, i1 = i0 + 1;
        int e0 = min(beg + i0, E - 1);
        int e1 = min(beg + i1, E - 1);
        bool ok0 = i0 < cnt, ok1 = i1 < cnt;
        int u0 = ok0 ? (int)csr[e0] : 0;
        int u1 = ok1 ? (int)csr[e1] : 0;
        float s0, s1;
        if (PRESCALED) { s0 = ok0 ? 1.f : 0.f;        s1 = ok1 ? 1.f : 0.f; }
        else           { s0 = ok0 ? dinv[u0] : 0.f;   s1 = ok1 ? dinv[u1] : 0.f; }
        uint4 q0 = G4[(size_t)u0 * 8 + cl];
        uint4 q1 = G4[(size_t)u1 * 8 + cl];
        a0 = fmaf(bf_lo(q0.x), s0, a0); a1 = fmaf(bf_hi(q0.x), s0, a1);
        a2 = fmaf(bf_lo(q0.y), s0, a2); a3 = fmaf(bf_hi(q0.y), s0, a3);
        a4 = fmaf(bf_lo(q0.z), s0, a4); a5 = fmaf(bf_hi(q0.z), s0, a5);
        a6 = fmaf(bf_lo(q0.w), s0, a6); a7 = fmaf(bf_hi(q0.w), s0, a7);
        b0 = fmaf(bf_lo(q1.x), s1, b0); b1 = fmaf(bf_hi(q1.x), s1, b1);
        b2 = fmaf(bf_lo(q1.y), s1, b2); b3 = fmaf(bf_hi(q1.y), s1, b3);
        b4 = fmaf(bf_lo(q1.z), s1, b4); b5 = fmaf(bf_hi(q1.z), s1, b5);
        b6 = fmaf(bf_lo(q1.w), s1, b6); b7 = fmaf(bf_hi(q1.w), s1, b7);
    }
    a0 += b0; a1 += b1; a2 += b2; a3 += b3;
    a4 += b4; a5 += b5; a6 += b6; a7 += b7;
    if (valid) {
        uint4 q = G4[(size_t)v * 8 + cl];   // self-loop term
        float d = dinv[v];
        float sv = PRESCALED ? 1.f : d;
        float o0 = (a0 + bf_lo(q.x) * sv) * d, o1 = (a1 + bf_hi(q.x) * sv) * d;
        float o2 = (a2 + bf_lo(q.y) * sv) * d, o3 = (a3 + bf_hi(q.y) * sv) * d;
        float o4 = (a4 + bf_lo(q.z) * sv) * d, o5 = (a5 + bf_hi(q.z) * sv) * d;
        float o6 = (a6 + bf_lo(q.w) * sv) * d, o7 = (a7 + bf_hi(q.w) * sv) * d;
        if (relu) {
            o0 = fmaxf(o0, 0.f); o1 = fmaxf(o1, 0.f); o2 = fmaxf(o2, 0.f);
            o3 = fmaxf(o3, 0.f); o4 = fmaxf(o4, 0.f); o5 = fmaxf(o5, 0.f);
            o6 = fmaxf(o6, 0.f); o7 = fmaxf(o7, 0.f);
        }
        if (F32OUT) {
            float4 w0 = {o0, o1, o2, o3}, w1 = {o4, o5, o6, o7};
            ((float4*)Out)[(size_t)v * 16 + cl * 2]     = w0;
            ((float4*)Out)[(size_t)v * 16 + cl * 2 + 1] = w1;
        } else {
            uint4 p;
            p.x = pack2bf(o0, o1); p.y = pack2bf(o2, o3);
            p.z = pack2bf(o4, o5); p.w = pack2bf(o6, o7);
            ((uint4*)Out)[(size_t)v * 8 + cl] = p;
        }
    }
}

// ---------- GEMM (bf16 input, K=64) + dinv prescale -> bf16 ----------
__global__ __launch_bounds__(256) void gemm_bf16_kernel(
        const unsigned short* __restrict__ Xbf, const float* __restrict__ W,
        const float* __restrict__ dinv, unsigned short* __restrict__ G, int N) {
    constexpr int XLDU = 36;
    __shared__ unsigned int Xs[64 * XLDU];  // 9216 B
    __shared__ float Wls[64 * CH];          // 16384 B
    int tid = threadIdx.x;
    int tx  = tid & 15;
    int ty  = tid >> 4;
    int row_tile = blockIdx.x * 64;
    int r0 = ty * 4;
    float acc[4][4] = {{0.f}};

#pragma unroll
    for (int t = 0; t < 2; ++t) {
        int idx = tid + t * 256;
        int row = idx >> 3;
        int k4  = idx & 7;
        int grow = row_tile + row;
        uint4 v = ((const uint4*)Xbf)[(size_t)min(grow, N - 1) * 8 + k4];
        *(uint4*)&Xs[row * XLDU + 4 * k4] = v;
    }
#pragma unroll
    for (int t = 0; t < 4; ++t) {
        int idx = tid + t * 256;
        *(float4*)&Wls[idx * 4] = ((const float4*)W)[idx];
    }
    __syncthreads();
#pragma unroll
    for (int kk = 0; kk < 64; kk += 4) {
        float xr[4][4], wr[4][4];
#pragma unroll
        for (int i = 0; i < 4; ++i) {
            uint2 q = *(const uint2*)&Xs[(r0 + i) * XLDU + (kk >> 1)];
            xr[i][0] = bf_lo(q.x); xr[i][1] = bf_hi(q.x);
            xr[i][2] = bf_lo(q.y); xr[i][3] = bf_hi(q.y);
        }
#pragma unroll
        for (int j = 0; j < 4; ++j) {
            float4 v = *(const float4*)&Wls[(kk + j) * CH + 4 * tx];
            wr[j][0] = v.x; wr[j][1] = v.y; wr[j][2] = v.z; wr[j][3] = v.w;
        }
#pragma unroll
        for (int i = 0; i < 4; ++i)
#pragma unroll
            for (int j = 0; j < 4; ++j)
#pragma unroll
                for (int c = 0; c < 4; ++c)
                    acc[i][c] = fmaf(xr[i][j], wr[j][c], acc[i][c]);
    }
#pragma unroll
    for (int i = 0; i < 4; ++i) {
        int r = row_tile + r0 + i;
        if (r < N) {
            float d = dinv[r];
            ushort4 o;
            o.x = f2bf_rne(acc[i][0] * d);
            o.y = f2bf_rne(acc[i][1] * d);
            o.z = f2bf_rne(acc[i][2] * d);
            o.w = f2bf_rne(acc[i][3] * d);
            ((ushort4*)G)[(size_t)r * 16 + tx] = o;
        }
    }
}

// ---------- fused mean-pool (bf16 h3) + linear head ----------
__global__ __launch_bounds__(64) void pool_head_kernel(
        const unsigned short* __restrict__ H, const int* __restrict__ gptr,
        const float* __restrict__ Wl, const float* __restrict__ bl,
        float* __restrict__ out, int NG) {
    int g = blockIdx.x;
    int lane = threadIdx.x;  // 64 = CH
    int s = gptr[g], e = gptr[g + 1];
    float acc = 0.f;
    for (int v = s; v < e; ++v) {
        unsigned int u = (unsigned int)H[(size_t)v * CH + lane];
        acc += __uint_as_float(u << 16);
    }
    float c = (float)(e - s);
    float mean = (c > 0.f) ? acc / c : 0.f;
    for (int o = 0; o < 10; ++o) {
        float t = mean * Wl[lane * 10 + o];
        for (int off = 32; off > 0; off >>= 1) t += __shfl_down(t, off);
        if (lane == 0) out[g * 10 + o] = t + bl[o];
    }
}

extern "C" void kernel_launch(void* const* d_in, const int* in_sizes, int n_in,
                              void* d_out, int out_size, void* d_ws, size_t ws_size,
                              hipStream_t stream) {
    const float* x     = (const float*)d_in[0];
    const int*   ei    = (const int*)d_in[1];
    const int*   batch = (const int*)d_in[2];
    const float* W1    = (const float*)d_in[3];
    const float* W2    = (const float*)d_in[4];
    const float* W3    = (const float*)d_in[5];
    const float* Wl    = (const float*)d_in[6];
    const float* bl    = (const float*)d_in[7];
    float* out = (float*)d_out;

    const int N  = in_sizes[0] / 128;  // 50000 (< 65536)
    const int E  = in_sizes[1] / 2;    // 1250000
    const int NG = out_size / 10;      // 500

    const int* src = ei;
    const int* dst = ei + E;

    const int cb = (E + CHUNK - 1) / CHUNK;  // 306

    // workspace carve-out (256B aligned)
    char* ws = (char*)d_ws;
    size_t off = 0;
    auto alloc = [&](size_t bytes) -> void* {
        void* p = ws + off;
        off += bytes;
        off = (off + 255) & ~(size_t)255;
        return p;
    };
    int*   bucket_cnt  = (int*)alloc((size_t)NBUCK * 4);
    int*   bucket_base = (int*)alloc((size_t)(NBUCK + 1) * 4);
    int*   cursor      = (int*)alloc((size_t)NBUCK * 4);
    unsigned short* csr = (unsigned short*)alloc((size_t)(E + 64) * 2);
    int*   rowptr = (int*)alloc((size_t)(N + 1) * 4);
    float* dinv   = (float*)alloc((size_t)N * 4);
    int*   gptrb  = (int*)alloc((size_t)(NG + 1) * 4);
    unsigned short* GA = (unsigned short*)alloc((size_t)N * CH * 2);  // 6.4MB
    unsigned short* GB = (unsigned short*)alloc((size_t)N * CH * 2);  // 6.4MB
    // pairs (5MB) alias GB: bin writes pairs, sort consumes, THEN agg1 writes GB.
    unsigned int* pairs = (unsigned int*)GB;

    hipMemsetAsync(bucket_cnt, 0, (size_t)NBUCK * 4, stream);

    int gb = (N + 63) / 64;            // 782 gemm tiles
    int ab = ((N + 7) / 8 + 3) / 4;    // agg: 8 nodes/wave, 4 waves/block

    hist_kernel<<<cb, 256, 0, stream>>>(dst, bucket_cnt, E);
    scan_gptr_kernel<<<2, 256, 0, stream>>>(bucket_cnt, bucket_base, cursor,
                                            rowptr, batch, gptrb, N, E, NG);
    // K1: gemm1 (raw messages -> GA) overlapped with bin (pairs)
    gemm1_bin_kernel<128><<<gb + cb, 256, 0, stream>>>(x, W1, GA, N,
                                                       src, dst, cursor, pairs, E, gb);
    bucket_sort_kernel<<<NBUCK, 256, 0, stream>>>(pairs, bucket_base, csr, rowptr, dinv, N);

    // layer 1 aggregate (messages NOT prescaled -> multiply dinv[u] per edge)
    aggregate_kernel<false, false><<<ab, 256, 0, stream>>>(GA, rowptr, csr, dinv,
                                                           GB, N, E, 1);
    // layer 2
    gemm_bf16_kernel<<<gb, 256, 0, stream>>>(GB, W2, dinv, GA, N);
    aggregate_kernel<true, false><<<ab, 256, 0, stream>>>(GA, rowptr, csr, dinv,
                                                          GB, N, E, 1);
    // layer 3
    gemm_bf16_kernel<<<gb, 256, 0, stream>>>(GB, W3, dinv, GA, N);
    // final aggregate -> bf16 h3 into GB (no relu)
    aggregate_kernel<true, false><<<ab, 256, 0, stream>>>(GA, rowptr, csr, dinv,
                                                          GB, N, E, 0);

    // mean pool (bf16) + linear head
    pool_head_kernel<<<NG, 64, 0, stream>>>(GB, gptrb, Wl, bl, out, NG);
}